// Round 1
// 20465.154 us; speedup vs baseline: 1.2835x; 1.2835x over previous
//
#include <hip/hip_runtime.h>

// Problem constants
#define Bn 32
#define Tn 1024
#define Dn 512
#define Hn 512
#define Vn 64
#define Sn 128
#define NTS 8          // t-slices per batch = group size
#define TT 128         // T per block
#define NU 64          // H-units per block
#define NTHREADS 512
#define KIH 576        // W_ih cols (V + H)

#define LDS_BYTES 139264
#define OUT_ATT ((size_t)Sn * Bn * Vn)

struct F8 { float4 a, b; };

__device__ __forceinline__ float bfu(unsigned short u){ return __uint_as_float(((unsigned int)u)<<16); }
__device__ __forceinline__ float bflo(unsigned int u){ return __uint_as_float(u<<16); }
__device__ __forceinline__ float bfhi(unsigned int u){ return __uint_as_float(u & 0xffff0000u); }
__device__ __forceinline__ unsigned short f2bf(float f){
  unsigned int x = __float_as_uint(f);
  return (unsigned short)((x + 0x7fffu + ((x>>16)&1u)) >> 16);   // RNE
}

// overloaded loads: 8 input elements -> 8 f32
__device__ __forceinline__ F8 ld8(const unsigned short* p){
  uint4 q = *(const uint4*)p;
  F8 r;
  r.a = make_float4(bflo(q.x), bfhi(q.x), bflo(q.y), bfhi(q.y));
  r.b = make_float4(bflo(q.z), bfhi(q.z), bflo(q.w), bfhi(q.w));
  return r;
}
__device__ __forceinline__ F8 ld8(const float* p){
  F8 r; r.a = *(const float4*)p; r.b = *(const float4*)(p+4); return r;
}
__device__ __forceinline__ float ldv(const unsigned short* p){ return bfu(*p); }
__device__ __forceinline__ float ldv(const float* p){ return *p; }
__device__ __forceinline__ void st(unsigned short* p, float v){ *p = f2bf(v); }
__device__ __forceinline__ void st(float* p, float v){ *p = v; }

__device__ __forceinline__ float dot8(F8 w, float4 a, float4 b){
  return w.a.x*a.x + w.a.y*a.y + w.a.z*a.z + w.a.w*a.w
       + w.b.x*b.x + w.b.y*b.y + w.b.z*b.z + w.b.w*b.w;
}
template<typename T>
__device__ __forceinline__ float dot64g(const T* __restrict__ w, const float* x){
  const float4* x4 = (const float4*)x;
  float acc = 0.f;
#pragma unroll
  for(int i=0;i<8;i++) acc += dot8(ld8(w+8*i), x4[2*i], x4[2*i+1]);
  return acc;
}

// clamped activations: no exp-overflow path exists (clamps are exact at f32 precision)
__device__ __forceinline__ float sigm(float x){
  x = fminf(fmaxf(x, -30.f), 30.f); return 1.f/(1.f + expf(-x));
}
__device__ __forceinline__ float tnh(float x){
  return tanhf(fminf(fmaxf(x, -20.f), 20.f));
}

template<bool B> struct Sel { using T = unsigned short; };
template<> struct Sel<false> { using T = float; };

// ---- relaxed agent-scope atomics for cross-XCD ws data ----
// RELAXED (not acq/rel) => no full-L2 writeback/invalidate. Data is coherent at
// the LLC (sc1); ordering is provided by the vmcnt(0) drain that __syncthreads
// performs before s_barrier (write-ack from the coherence point), plus the
// barrier protocol below.
__device__ __forceinline__ void aput(float* p, float v){
  __hip_atomic_store(p, v, __ATOMIC_RELAXED, __HIP_MEMORY_SCOPE_AGENT);
}
__device__ __forceinline__ float aget(const float* p){
  return __hip_atomic_load(p, __ATOMIC_RELAXED, __HIP_MEMORY_SCOPE_AGENT);
}

// 8-block group generation barrier (monotonic counters, relaxed atomics only).
// bar[0] = cumulative arrivals, bar[1] = generation. No reset store -> no
// store-store ordering hazard. Groups co-resident by LDS sizing: 1 block/CU.
__device__ __forceinline__ void gbar(unsigned int* bar){
  asm volatile("s_waitcnt vmcnt(0)" ::: "memory");  // prior ws stores acked at LLC
  __syncthreads();
  if(threadIdx.x==0){
    unsigned int g = __hip_atomic_load(bar+1, __ATOMIC_RELAXED, __HIP_MEMORY_SCOPE_AGENT);
    unsigned int p = __hip_atomic_fetch_add(bar, 1u, __ATOMIC_RELAXED, __HIP_MEMORY_SCOPE_AGENT);
    if(p == g*NTS + (NTS-1)){
      __hip_atomic_store(bar+1, g+1u, __ATOMIC_RELAXED, __HIP_MEMORY_SCOPE_AGENT);
    } else {
      while(__hip_atomic_load(bar+1, __ATOMIC_RELAXED, __HIP_MEMORY_SCOPE_AGENT) == g)
        __builtin_amdgcn_s_sleep(2);
    }
  }
  __syncthreads();
  asm volatile("" ::: "memory");
}

// dtype probe: b_ih ~ N(0, 0.01^2). If data is bf16, every even-indexed short decodes
// to |v|<0.5. If data is f32, even shorts are raw mantissa bits -> random exponents
// (P[all 512 < 0.5] ~ 1e-158). flag: 1 = bf16, 2 = f32.
__global__ void dtype_probe(const unsigned short* __restrict__ b3, unsigned int* flag){
  const int t = threadIdx.x;
  bool ok = true;
#pragma unroll
  for(int i=0;i<8;i++){
    float v = bfu(b3[2*(t*8+i)]);
    ok = ok && (v == v) && (fabsf(v) < 0.5f);
  }
  unsigned long long m = __ballot(ok);
  if(t == 0)
    __hip_atomic_store(flag, (m == ~0ull) ? 1u : 2u, __ATOMIC_RELEASE, __HIP_MEMORY_SCOPE_AGENT);
}

template<bool BF>
__global__ __launch_bounds__(NTHREADS, 2)
void speller_persist(const void* __restrict__ lf_,   const void* __restrict__ wih_,
                     const void* __restrict__ whh_,  const void* __restrict__ bih_,
                     const void* __restrict__ bhh_,  const void* __restrict__ bout_pad,
                     const void* __restrict__ bout_, void* __restrict__ out_,
                     float* __restrict__ ws)
{
  // self-select on the probed dtype; the wrong instantiation exits immediately
  {
    unsigned int fl = __hip_atomic_load((unsigned int*)ws + 512, __ATOMIC_ACQUIRE, __HIP_MEMORY_SCOPE_AGENT);
    if(fl != (BF ? 1u : 2u)) return;
  }
  using T = typename Sel<BF>::T;
  const T* lf   = (const T*)lf_;
  const T* wih  = (const T*)wih_;
  const T* whh  = (const T*)whh_;
  const T* bih  = (const T*)bih_;
  const T* bhh  = (const T*)bhh_;
  const T* wout = (const T*)bout_pad;
  const T* bout = (const T*)bout_;
  T* out = (T*)out_;

  const int tid = threadIdx.x;
  const int b   = (int)(blockIdx.x >> 3);   // batch
  const int ts  = (int)(blockIdx.x & 7);    // t-slice / unit-slice

  extern __shared__ char smem[];
  // tile region [0,131072): BF path = bf16 [128][512]; f32 path = f32 [64][512] XOR-swizzled
  unsigned short* lf_s = (unsigned short*)smem;
  float* epart = (float*)(smem + 131072);                 // [512] energy wave-partials (f32 path)
  float* h_s   = epart + 512;                             // [512] h(s)
  float* ctx_s = h_s + 512;                               // [512] ctx(s-1)
  float* e_s   = ctx_s + 512;                             // [128] raw energies (persist over barrier)
  float* p_s   = e_s + 128;                               // [128] exp(e - m_local)
  float* lg_s  = p_s + 128;                               // [64] logits
  float* red_s = lg_s + 64;                               // [0..7]=fac,[8]=m,[9]=l,[10]=m_loc,[16..23]=mst,[24..31]=lst
  float* c_s   = red_s + 32;                              // [64] LSTM cell state
  int*   i_s   = (int*)(c_s + 64);                        // [0] = prev argmax

  // ws floats: [0,498)=barriers (u32), [512]=dtype flag (u32), [1024,17408)=hbuf,
  // [17408,17664)=mst, [17664,17920)=lst, [17920,149024)=ctxp  (~596 KB)
  unsigned int* bar = (unsigned int*)ws + (size_t)b*16;
  float* hbuf = ws + 1024  + (size_t)b*Hn;
  float* mst  = ws + 17408 + (size_t)b*NTS;
  float* lst  = ws + 17664 + (size_t)b*NTS;
  float* ctxp = ws + 17920 + (size_t)b*NTS*Dn;

  // f32 path: rows 64..127 of this block's LF slice live in registers,
  // column-major: thread owns column d = tid, lfreg[j] = LF[ts*128+64+j][tid]
  float lfreg[64];

  // ---------------- init ----------------
  if constexpr (BF){
    const uint4* s4 = (const uint4*)((const unsigned short*)lf_ + ((size_t)b*Tn + (size_t)ts*TT) * Dn);
    uint4* d4 = (uint4*)lf_s;
#pragma unroll
    for(int i=0;i<16;i++) d4[tid + i*NTHREADS] = s4[tid + i*NTHREADS];
  } else {
    // rows 0..63 -> swizzled f32 LDS tile: float4 slot c stored at c ^ (row&7)
    const float4* s4 = (const float4*)((const float*)lf_ + ((size_t)b*Tn + (size_t)ts*TT) * Dn);
    float4* d4 = (float4*)smem;
#pragma unroll
    for(int i=0;i<16;i++){
      const int f = tid + i*NTHREADS;       // float4 index in [0,8192)
      const int row = f >> 7, cc = f & 127; // 128 float4 per row
      d4[(row << 7) | (cc ^ (row & 7))] = s4[f];
    }
    // rows 64..127 -> registers (coalesced column loads)
    const float* lfg = (const float*)lf_ + ((size_t)b*Tn + (size_t)ts*TT + 64) * Dn + tid;
#pragma unroll
    for(int j=0;j<64;j++) lfreg[j] = lfg[(size_t)j*Dn];
  }
  h_s[tid] = 0.f;
  if(tid < NU) c_s[tid] = 0.f;
  if(tid == 0) i_s[0] = 0;
  __syncthreads();

  for(int s = 0; s <= Sn; ++s){
    // ================= P phase =================
    if(s > 0){
      if(tid < NTS){ red_s[16+tid] = aget(&mst[tid]); red_s[24+tid] = aget(&lst[tid]); }
      __syncthreads();
      if(tid == 0){
        float m = -3.0e38f;
#pragma unroll
        for(int j=0;j<NTS;j++) m = fmaxf(m, red_s[16+j]);
        float l = 0.f;
#pragma unroll
        for(int j=0;j<NTS;j++){ float fac = expf(red_s[16+j]-m); red_s[j]=fac; l += fac*red_s[24+j]; }
        red_s[8]=m; red_s[9]=l;
      }
      __syncthreads();
      const float gm = red_s[8];
      const float gl = red_s[9];
      {  // combine + normalize ctx(s-1) (identical in all 8 group blocks)
        float acc = 0.f;
#pragma unroll
        for(int j=0;j<NTS;j++) acc += red_s[j] * aget(&ctxp[(size_t)j*Dn + tid]);
        ctx_s[tid] = acc / gl;
      }
      if(tid < TT){  // attn(s-1) for this slice
        float a = expf(e_s[tid] - gm) / gl;
        st(out + OUT_ATT + ((size_t)(s-1)*Bn + b)*Tn + (size_t)ts*TT + tid, a);
      }
      __syncthreads();
      {  // logits(s-1) = W_out @ [h; ctx] + b_out   (W_out is L2-resident now)
        const int j = tid >> 3, ks = tid & 7;
        const T* wr = wout + (size_t)j*(2*Hn) + ks*128;
        float acc;
        if(ks < 4) acc = dot64g(wr, h_s + ks*128)       + dot64g(wr+64, h_s + ks*128 + 64);
        else       acc = dot64g(wr, ctx_s + (ks-4)*128) + dot64g(wr+64, ctx_s + (ks-4)*128 + 64);
#pragma unroll
        for(int off=1; off<8; off<<=1) acc += __shfl_xor(acc, off);
        if(ks==0) lg_s[j] = acc + ldv(bout + j);
      }
      __syncthreads();
      if(tid < Vn){  // wave 0: log_softmax + first-index argmax
        const float lv = lg_s[tid];
        float mv = lv; int mi = tid;
#pragma unroll
        for(int off=1; off<64; off<<=1){
          float ov = __shfl_xor(mv, off);
          int   oi = __shfl_xor(mi, off);
          if(ov > mv || (ov == mv && oi < mi)){ mv = ov; mi = oi; }
        }
        float se = expf(lv - mv);
#pragma unroll
        for(int off=1; off<64; off<<=1) se += __shfl_xor(se, off);
        const float logp = lv - mv - logf(se);
        if(ts == 0) st(out + ((size_t)(s-1)*Bn + b)*Vn + tid, logp);
        if(tid == 0) i_s[0] = mi;
      }
      __syncthreads();
    } else {
      // s==0: x0 = [onehot(0), LF[:,0,:]]
      ctx_s[tid] = ldv(lf + (size_t)b*Tn*Dn + tid);
      __syncthreads();
    }

    if(s == Sn) break;

    // gates: units uu = ts*64+u ; rows i,f,g,o ; K=1024 split 8 ways across ks
    {
      const int u  = tid >> 3;
      const int ks = tid & 7;
      const int uu = ts*NU + u;
      const T* wi0 = wih + (size_t)(       uu)*KIH + 64 + ks*64;
      const T* wi1 = wih + (size_t)(  Hn + uu)*KIH + 64 + ks*64;
      const T* wi2 = wih + (size_t)(2*Hn + uu)*KIH + 64 + ks*64;
      const T* wi3 = wih + (size_t)(3*Hn + uu)*KIH + 64 + ks*64;
      const T* wh0 = whh + (size_t)(       uu)*Hn + ks*64;
      const T* wh1 = whh + (size_t)(  Hn + uu)*Hn + ks*64;
      const T* wh2 = whh + (size_t)(2*Hn + uu)*Hn + ks*64;
      const T* wh3 = whh + (size_t)(3*Hn + uu)*Hn + ks*64;
      const float4* xc = (const float4*)(ctx_s + ks*64);
      const float4* xh = (const float4*)(h_s   + ks*64);
      float a0=0.f,a1=0.f,a2=0.f,a3=0.f;
#pragma unroll
      for(int i=0;i<8;i++){
        float4 p0 = xc[2*i], p1 = xc[2*i+1];
        a0 += dot8(ld8(wi0+8*i), p0, p1);
        a1 += dot8(ld8(wi1+8*i), p0, p1);
        a2 += dot8(ld8(wi2+8*i), p0, p1);
        a3 += dot8(ld8(wi3+8*i), p0, p1);
      }
#pragma unroll
      for(int i=0;i<8;i++){
        float4 p0 = xh[2*i], p1 = xh[2*i+1];
        a0 += dot8(ld8(wh0+8*i), p0, p1);
        a1 += dot8(ld8(wh1+8*i), p0, p1);
        a2 += dot8(ld8(wh2+8*i), p0, p1);
        a3 += dot8(ld8(wh3+8*i), p0, p1);
      }
#pragma unroll
      for(int off=1; off<8; off<<=1){
        a0 += __shfl_xor(a0, off);
        a1 += __shfl_xor(a1, off);
        a2 += __shfl_xor(a2, off);
        a3 += __shfl_xor(a3, off);
      }
      if(ks == 0){
        const int pidx = i_s[0];
        const int r0 = uu, r1 = Hn+uu, r2 = 2*Hn+uu, r3 = 3*Hn+uu;
        float gi = a0 + ldv(wih + (size_t)r0*KIH + pidx) + ldv(bih+r0) + ldv(bhh+r0);
        float gf = a1 + ldv(wih + (size_t)r1*KIH + pidx) + ldv(bih+r1) + ldv(bhh+r1);
        float gg = a2 + ldv(wih + (size_t)r2*KIH + pidx) + ldv(bih+r2) + ldv(bhh+r2);
        float go = a3 + ldv(wih + (size_t)r3*KIH + pidx) + ldv(bih+r3) + ldv(bhh+r3);
        gi = sigm(gi);
        gf = sigm(gf);
        gg = tnh(gg);
        go = sigm(go);
        float c = gf*c_s[u] + gi*gg;
        c_s[u] = c;
        aput(&hbuf[uu], go * tnh(c));
      }
    }
    gbar(bar);

    // ================= Q phase =================
    h_s[tid] = aget(&hbuf[tid]);
    __syncthreads();
    if constexpr (BF){
      {  // energies for 2 local t's per thread (t2 = tid>>3, q = K-octant)
        const int t2 = tid >> 3;
        const int q  = tid & 7;
        const float4* hq = (const float4*)(h_s + q*64);
        float ea=0.f, eb=0.f;
        const unsigned short* la = lf_s + (size_t)(2*t2  )*Dn + q*64;
        const unsigned short* lb = lf_s + (size_t)(2*t2+1)*Dn + q*64;
#pragma unroll
        for(int i=0;i<8;i++){
          float4 p0 = hq[2*i], p1 = hq[2*i+1];
          ea += dot8(ld8(la+8*i), p0, p1);
          eb += dot8(ld8(lb+8*i), p0, p1);
        }
#pragma unroll
        for(int off=1; off<8; off<<=1){ ea += __shfl_xor(ea,off); eb += __shfl_xor(eb,off); }
        if(q==0){ e_s[2*t2] = ea; e_s[2*t2+1] = eb; }
      }
      __syncthreads();
      if(tid < 64){   // slice max
        float v = fmaxf(e_s[tid], e_s[tid+64]);
#pragma unroll
        for(int off=1; off<64; off<<=1) v = fmaxf(v, __shfl_xor(v,off));
        if(tid==0) red_s[10] = v;
      }
    } else {
      {  // rows 0..63: one row per thread from swizzled f32 LDS tile
        const int t1 = tid >> 3, q = tid & 7, mm = t1 & 7;
        const float4* lrow = (const float4*)smem + (size_t)t1*128;
        const float4* hq = (const float4*)(h_s + q*64);
        float ea = 0.f;
#pragma unroll
        for(int i=0;i<8;i++){
          const int c0 = q*16 + 2*i;
          F8 wv; wv.a = lrow[c0 ^ mm]; wv.b = lrow[(c0+1) ^ mm];
          ea += dot8(wv, hq[2*i], hq[2*i+1]);
        }
#pragma unroll
        for(int off=1; off<8; off<<=1) ea += __shfl_xor(ea, off);
        if(q==0) e_s[t1] = ea;
      }
      {  // rows 64..127 from registers: butterfly reduce across the wave per t
        const int lane = tid & 63;
        const float h_own = h_s[tid];
        float mine = 0.f;
#pragma unroll
        for(int j=0;j<64;j++){
          float v = h_own * lfreg[j];
#pragma unroll
          for(int off=1; off<64; off<<=1) v += __shfl_xor(v, off);
          if(lane == j) mine = v;
        }
        epart[tid] = mine;   // [wave][lane] = partial for t=64+lane over wave's d-range
      }
      __syncthreads();
      if(tid < 64){   // cross-wave combine + slice max
        float s2 = 0.f;
#pragma unroll
        for(int w2=0; w2<8; w2++) s2 += epart[(w2<<6) + tid];
        e_s[64 + tid] = s2;
        float v = fmaxf(e_s[tid], s2);
#pragma unroll
        for(int off=1; off<64; off<<=1) v = fmaxf(v, __shfl_xor(v,off));
        if(tid==0) red_s[10] = v;
      }
    }
    __syncthreads();
    if(tid < TT) p_s[tid] = expf(e_s[tid] - red_s[10]);
    __syncthreads();
    if(tid < 64){   // slice sumexp -> publish (m_s, l_s)
      float v = p_s[tid] + p_s[tid+64];
#pragma unroll
      for(int off=1; off<64; off<<=1) v += __shfl_xor(v,off);
      if(tid==0){ aput(&mst[ts], red_s[10]); aput(&lst[ts], v); }
    }
    {  // ctx partial: thread owns one d, sweep 128 t's (LDS half + register half)
      float acc = 0.f;
      if constexpr (BF){
        const unsigned short* col = lf_s + tid;
#pragma unroll 4
        for(int t=0;t<TT;t++) acc += p_s[t] * bfu(col[(size_t)t*Dn]);
      } else {
        const float* base = (const float*)smem;
        const int cs = tid >> 2, cr = tid & 3;
#pragma unroll
        for(int t=0;t<64;t++)
          acc += p_s[t] * base[(size_t)t*Dn + (((cs ^ (t&7))<<2) | cr)];
#pragma unroll
        for(int j=0;j<64;j++) acc += p_s[64+j] * lfreg[j];
      }
      aput(&ctxp[(size_t)ts*Dn + tid], acc);
    }
    gbar(bar);
  }
}

extern "C" void kernel_launch(void* const* d_in, const int* in_sizes, int n_in,
                              void* d_out, int out_size, void* d_ws, size_t ws_size,
                              hipStream_t stream) {
  (void)in_sizes; (void)n_in; (void)out_size; (void)ws_size;
  float* ws = (float*)d_ws;

  hipFuncSetAttribute(reinterpret_cast<const void*>(&speller_persist<true>),
                      hipFuncAttributeMaxDynamicSharedMemorySize, LDS_BYTES);
  hipFuncSetAttribute(reinterpret_cast<const void*>(&speller_persist<false>),
                      hipFuncAttributeMaxDynamicSharedMemorySize, LDS_BYTES);
  // barriers + flag live in the first 4 KB (d_ws is poisoned 0xAA before every launch)
  hipMemsetAsync(d_ws, 0, 4096, stream);
  // probe b_ih (d_in[3]) to decide bf16 vs f32; writes flag at u32 index 512
  dtype_probe<<<dim3(1), dim3(64), 0, stream>>>((const unsigned short*)d_in[3],
                                                (unsigned int*)d_ws + 512);
  speller_persist<true><<<dim3(Bn*NTS), dim3(NTHREADS), LDS_BYTES, stream>>>(
      d_in[0], d_in[1], d_in[2], d_in[3], d_in[4], d_in[5], d_in[6], d_out, ws);
  speller_persist<false><<<dim3(Bn*NTS), dim3(NTHREADS), LDS_BYTES, stream>>>(
      d_in[0], d_in[1], d_in[2], d_in[3], d_in[4], d_in[5], d_in[6], d_out, ws);
}